// Round 3
// baseline (272.999 us; speedup 1.0000x reference)
//
#include <hip/hip_runtime.h>
#include <math.h>

#define BATCH   32768
#define NCLS    1000
#define NC4     250              // float4 chunks per row
#define NBLOCKS 2048
#define NWAVES  (NBLOCKS * 4)    // 8192 waves = chip wave capacity
#define RPW     (BATCH / NWAVES) // 4 rows per wave

// Full-wave (64-lane) sum via DPP adds on the VALU pipe — no LDS/ds ops.
// After the chain, lane 63 holds the total.
__device__ __forceinline__ float wave_sum_dpp(float v) {
    int x;
    x = __builtin_amdgcn_update_dpp(0, __float_as_int(v), 0x111, 0xf, 0xf, true); // row_shr:1
    v += __int_as_float(x);
    x = __builtin_amdgcn_update_dpp(0, __float_as_int(v), 0x112, 0xf, 0xf, true); // row_shr:2
    v += __int_as_float(x);
    x = __builtin_amdgcn_update_dpp(0, __float_as_int(v), 0x114, 0xf, 0xf, true); // row_shr:4
    v += __int_as_float(x);
    x = __builtin_amdgcn_update_dpp(0, __float_as_int(v), 0x118, 0xf, 0xf, true); // row_shr:8
    v += __int_as_float(x);
    x = __builtin_amdgcn_update_dpp(0, __float_as_int(v), 0x142, 0xa, 0xf, true); // row_bcast:15 -> rows 1,3
    v += __int_as_float(x);
    x = __builtin_amdgcn_update_dpp(0, __float_as_int(v), 0x143, 0xc, 0xf, true); // row_bcast:31 -> rows 2,3
    v += __int_as_float(x);
    return v;
}

__device__ __forceinline__ float bcast63(float v) {
    return __int_as_float(__builtin_amdgcn_readlane(__float_as_int(v), 63));
}

// Wave-per-row, 4 rows/wave. Branchless clamped vector loads (full MLP),
// one __expf per element, single DPP reduction (sp) per row; sn reduction
// deferred via per-lane accumulator acc += sn_lane * SP_total.
__global__ __launch_bounds__(256, 4) void lsep_row_kernel(
    const float* __restrict__ x,
    const int*   __restrict__ t,
    float* __restrict__ wave_out) {

    const int tid   = threadIdx.x;
    const int lane  = tid & 63;
    const int gwave = blockIdx.x * 4 + (tid >> 6);

    float acc = 0.0f;  // per-lane: sum over rows of sn_lane(row) * SP(row)

    #pragma unroll
    for (int r = 0; r < RPW; ++r) {
        const int row = gwave + r * NWAVES;
        const float4* xr = (const float4*)(x + (size_t)row * NCLS);
        const int4*   tr = (const int4*)(t + (size_t)row * NCLS);

        // unconditional clamped loads -> compiler can issue all 8 up front
        float4 xv[4];
        int4   tv[4];
        #pragma unroll
        for (int j = 0; j < 4; ++j) {
            const int idx = lane + 64 * j;
            const int ci  = idx < NC4 ? idx : NC4 - 1;
            xv[j] = xr[ci];
            tv[j] = tr[ci];
        }

        float sn = 0.0f, sp = 0.0f;
        #pragma unroll
        for (int j = 0; j < 4; ++j) {
            const bool valid = (lane + 64 * j) < NC4;
            {   const bool isneg = tv[j].x == 0;
                float v = __expf(isneg ? xv[j].x : -xv[j].x);
                sn += (valid && isneg)  ? v : 0.0f;
                sp += (valid && !isneg) ? v : 0.0f; }
            {   const bool isneg = tv[j].y == 0;
                float v = __expf(isneg ? xv[j].y : -xv[j].y);
                sn += (valid && isneg)  ? v : 0.0f;
                sp += (valid && !isneg) ? v : 0.0f; }
            {   const bool isneg = tv[j].z == 0;
                float v = __expf(isneg ? xv[j].z : -xv[j].z);
                sn += (valid && isneg)  ? v : 0.0f;
                sp += (valid && !isneg) ? v : 0.0f; }
            {   const bool isneg = tv[j].w == 0;
                float v = __expf(isneg ? xv[j].w : -xv[j].w);
                sn += (valid && isneg)  ? v : 0.0f;
                sp += (valid && !isneg) ? v : 0.0f; }
        }

        const float SP = bcast63(wave_sum_dpp(sp));  // total s_pos of this row
        acc += sn * SP;
    }

    const float tot = wave_sum_dpp(acc);
    if (lane == 63) wave_out[gwave] = tot;
}

// Single block reduces NWAVES partials; fully unrolled loads.
__global__ __launch_bounds__(256) void lsep_reduce_kernel(
    const float* __restrict__ wave_out,
    float* __restrict__ out) {

    const int tid = threadIdx.x;
    const float4* r4 = (const float4*)wave_out;   // NWAVES/4 = 2048 float4

    float4 a[8];
    #pragma unroll
    for (int j = 0; j < 8; ++j)
        a[j] = r4[tid + 256 * j];

    float v = 0.0f;
    #pragma unroll
    for (int j = 0; j < 8; ++j)
        v += (a[j].x + a[j].y) + (a[j].z + a[j].w);

    #pragma unroll
    for (int off = 32; off > 0; off >>= 1)
        v += __shfl_down(v, off, 64);

    __shared__ float sv[4];
    const int wave = tid >> 6;
    const int lane = tid & 63;
    if (lane == 0) sv[wave] = v;
    __syncthreads();

    if (tid == 0) {
        float total = (sv[0] + sv[1]) + (sv[2] + sv[3]);
        out[0] = log1pf(total);
    }
}

extern "C" void kernel_launch(void* const* d_in, const int* in_sizes, int n_in,
                              void* d_out, int out_size, void* d_ws, size_t ws_size,
                              hipStream_t stream) {
    const float* x = (const float*)d_in[0];
    const int*   t = (const int*)d_in[1];
    float* out     = (float*)d_out;
    float* wave_ws = (float*)d_ws;   // NWAVES floats = 32 KB

    lsep_row_kernel<<<NBLOCKS, 256, 0, stream>>>(x, t, wave_ws);
    lsep_reduce_kernel<<<1, 256, 0, stream>>>(wave_ws, out);
}

// Round 4
// 272.315 us; speedup vs baseline: 1.0025x; 1.0025x over previous
//
#include <hip/hip_runtime.h>
#include <math.h>

#define BATCH   32768
#define NCLS    1000
#define NC4     250              // float4 chunks per row
#define NBLOCKS 2048
#define NWAVES  (NBLOCKS * 4)    // 8192 waves
#define RPW     (BATCH / NWAVES) // 4 rows per wave

// 64-lane sum via DPP adds (VALU pipe, no LDS). Lane 63 holds the total.
__device__ __forceinline__ float wave_sum_dpp(float v) {
    int x;
    x = __builtin_amdgcn_update_dpp(0, __float_as_int(v), 0x111, 0xf, 0xf, true); // row_shr:1
    v += __int_as_float(x);
    x = __builtin_amdgcn_update_dpp(0, __float_as_int(v), 0x112, 0xf, 0xf, true); // row_shr:2
    v += __int_as_float(x);
    x = __builtin_amdgcn_update_dpp(0, __float_as_int(v), 0x114, 0xf, 0xf, true); // row_shr:4
    v += __int_as_float(x);
    x = __builtin_amdgcn_update_dpp(0, __float_as_int(v), 0x118, 0xf, 0xf, true); // row_shr:8
    v += __int_as_float(x);
    x = __builtin_amdgcn_update_dpp(0, __float_as_int(v), 0x142, 0xa, 0xf, true); // row_bcast:15
    v += __int_as_float(x);
    x = __builtin_amdgcn_update_dpp(0, __float_as_int(v), 0x143, 0xc, 0xf, true); // row_bcast:31
    v += __int_as_float(x);
    return v;
}

__device__ __forceinline__ float bcast63(float v) {
    return __int_as_float(__builtin_amdgcn_readlane(__float_as_int(v), 63));
}

struct RowRegs {
    float4 xv[4];
    int4   tv[4];
};

__device__ __forceinline__ void load_row(const float* __restrict__ x,
                                         const int*   __restrict__ t,
                                         int row, int lane, RowRegs& R) {
    const float4* xr = (const float4*)(x + (size_t)row * NCLS);
    const int4*   tr = (const int4*)(t + (size_t)row * NCLS);
    #pragma unroll
    for (int j = 0; j < 4; ++j) {
        const int idx = lane + 64 * j;
        const int ci  = idx < NC4 ? idx : NC4 - 1;   // branchless clamp
        R.xv[j] = xr[ci];
        R.tv[j] = tr[ci];
    }
}

__device__ __forceinline__ void compute_row(const RowRegs& R, int lane, float& acc) {
    float sn = 0.0f, sp = 0.0f;
    #pragma unroll
    for (int j = 0; j < 4; ++j) {
        const bool valid = (lane + 64 * j) < NC4;
        {   const bool isneg = R.tv[j].x == 0;
            float v = __expf(isneg ? R.xv[j].x : -R.xv[j].x);
            sn += (valid && isneg)  ? v : 0.0f;
            sp += (valid && !isneg) ? v : 0.0f; }
        {   const bool isneg = R.tv[j].y == 0;
            float v = __expf(isneg ? R.xv[j].y : -R.xv[j].y);
            sn += (valid && isneg)  ? v : 0.0f;
            sp += (valid && !isneg) ? v : 0.0f; }
        {   const bool isneg = R.tv[j].z == 0;
            float v = __expf(isneg ? R.xv[j].z : -R.xv[j].z);
            sn += (valid && isneg)  ? v : 0.0f;
            sp += (valid && !isneg) ? v : 0.0f; }
        {   const bool isneg = R.tv[j].w == 0;
            float v = __expf(isneg ? R.xv[j].w : -R.xv[j].w);
            sn += (valid && isneg)  ? v : 0.0f;
            sp += (valid && !isneg) ? v : 0.0f; }
    }
    const float SP = bcast63(wave_sum_dpp(sp));  // row total s_pos
    acc += sn * SP;                              // defer sn reduction
}

// sched_barrier mask 0x407 = ALU|VALU|SALU|TRANS may cross; VMEM may NOT.
// Pins the 2-row double-buffered load schedule so >=8 loads stay in flight.
#define PIPE_FENCE() __builtin_amdgcn_sched_barrier(0x407)

__global__ __launch_bounds__(256, 4) void lsep_row_kernel(
    const float* __restrict__ x,
    const int*   __restrict__ t,
    float* __restrict__ wave_out) {

    const int tid   = threadIdx.x;
    const int lane  = tid & 63;
    const int gwave = blockIdx.x * 4 + (tid >> 6);

    const int r0 = gwave;
    const int r1 = gwave + NWAVES;
    const int r2 = gwave + 2 * NWAVES;
    const int r3 = gwave + 3 * NWAVES;

    float acc = 0.0f;   // per-lane: sum over rows of sn_lane * SP(row)
    RowRegs A, B;

    load_row(x, t, r0, lane, A);
    load_row(x, t, r1, lane, B);
    PIPE_FENCE();
    compute_row(A, lane, acc);
    load_row(x, t, r2, lane, A);
    PIPE_FENCE();
    compute_row(B, lane, acc);
    load_row(x, t, r3, lane, B);
    PIPE_FENCE();
    compute_row(A, lane, acc);
    PIPE_FENCE();
    compute_row(B, lane, acc);

    const float tot = wave_sum_dpp(acc);
    if (lane == 63) wave_out[gwave] = tot;
}

// Single block reduces NWAVES partials; fully unrolled loads.
__global__ __launch_bounds__(256) void lsep_reduce_kernel(
    const float* __restrict__ wave_out,
    float* __restrict__ out) {

    const int tid = threadIdx.x;
    const float4* r4 = (const float4*)wave_out;   // NWAVES/4 = 2048 float4

    float4 a[8];
    #pragma unroll
    for (int j = 0; j < 8; ++j)
        a[j] = r4[tid + 256 * j];

    float v = 0.0f;
    #pragma unroll
    for (int j = 0; j < 8; ++j)
        v += (a[j].x + a[j].y) + (a[j].z + a[j].w);

    #pragma unroll
    for (int off = 32; off > 0; off >>= 1)
        v += __shfl_down(v, off, 64);

    __shared__ float sv[4];
    const int wave = tid >> 6;
    const int lane = tid & 63;
    if (lane == 0) sv[wave] = v;
    __syncthreads();

    if (tid == 0) {
        float total = (sv[0] + sv[1]) + (sv[2] + sv[3]);
        out[0] = log1pf(total);
    }
}

extern "C" void kernel_launch(void* const* d_in, const int* in_sizes, int n_in,
                              void* d_out, int out_size, void* d_ws, size_t ws_size,
                              hipStream_t stream) {
    const float* x = (const float*)d_in[0];
    const int*   t = (const int*)d_in[1];
    float* out     = (float*)d_out;
    float* wave_ws = (float*)d_ws;   // NWAVES floats = 32 KB

    lsep_row_kernel<<<NBLOCKS, 256, 0, stream>>>(x, t, wave_ws);
    lsep_reduce_kernel<<<1, 256, 0, stream>>>(wave_ws, out);
}